// Round 5
// baseline (1594.806 us; speedup 1.0000x reference)
//
#include <hip/hip_runtime.h>
#include <hip/hip_bf16.h>

// out = (1-z)*hidden + z*n
//   r = sig(in·(w_ir+w_hr)^T + b_ir+b_hr)
//   z = sig(in·(w_iz+w_hz)^T + b_iz+b_hz)
//   n = sig(in·w_in^T + b_in + r*(in·w_hn^T + b_hn))
// Fast path: prepass folds/converts weights+input to bf16 in d_ws, then a
// global_load_lds-staged, counted-vmcnt double-buffered 4-gate fused GEMM.
// Round 5: block shrunk (BN 128->64/gate, acc 128->64 f32, LDS 80->48KB) so
// TWO blocks co-reside per CU (unified VGPR+AGPR <=128, launch_bounds(512,4))
// -> inter-block overlap hides barrier drains (m97/m114 mechanism).
// Fallback (ws too small): round-1 fp32-staged kernel (known passing).

#define BM 128
#define BN 128          // fallback kernel tile
#define FBN 64          // fast kernel: BN per gate
#define BK 32
#define THREADS 512
#define B_DIM 8192
#define D_DIM 4096
#define H_DIM 4096
#define NSTEP (D_DIM / BK)   // 128
#define LDSBUF 24576         // 8KB A + 4 x 4KB B

// ws layout (bytes)
#define WS_WR 0
#define WS_WZ 33554432
#define WS_WN 67108864
#define WS_WH 100663296
#define WS_A  134217728
#define WS_NEED 201326592ULL

typedef __attribute__((ext_vector_type(8))) short bf16x8;
typedef __attribute__((ext_vector_type(4))) float f32x4;
typedef __attribute__((ext_vector_type(4))) int i32x4;

__device__ __forceinline__ unsigned f2bf(float f) {
    union { float f; unsigned u; } v; v.f = f;
    return (v.u + 0x7FFFu + ((v.u >> 16) & 1u)) >> 16;   // RNE
}
__device__ __forceinline__ unsigned pk(float a, float b) {
    return (f2bf(a) & 0xFFFFu) | (f2bf(b) << 16);
}
__device__ __forceinline__ i32x4 pack8(float4 x, float4 y) {
    i32x4 r;
    r[0] = (int)pk(x.x, x.y); r[1] = (int)pk(x.z, x.w);
    r[2] = (int)pk(y.x, y.y); r[3] = (int)pk(y.z, y.w);
    return r;
}
__device__ __forceinline__ float sigmoidf_(float x) {
    return 1.0f / (1.0f + __expf(-x));
}
__device__ __forceinline__ void gld16(const void* g, void* l) {
    __builtin_amdgcn_global_load_lds(
        (const __attribute__((address_space(1))) unsigned*)g,
        (__attribute__((address_space(3))) unsigned*)l, 16, 0, 0);
}

// ---------------- prepass kernels ----------------
__global__ __launch_bounds__(256) void prep_w(
    const float* __restrict__ ir, const float* __restrict__ hr,
    const float* __restrict__ iz, const float* __restrict__ hz,
    const float* __restrict__ inw, const float* __restrict__ hn,
    i32x4* __restrict__ wr, i32x4* __restrict__ wz,
    i32x4* __restrict__ wn, i32x4* __restrict__ wh)
{
    const int i = blockIdx.x * 256 + threadIdx.x;     // chunk of 8 floats
    const float4* pir = (const float4*)ir; const float4* phr = (const float4*)hr;
    const float4* piz = (const float4*)iz; const float4* phz = (const float4*)hz;
    const float4* pin = (const float4*)inw; const float4* phn = (const float4*)hn;
    float4 a0 = pir[2*i], a1 = pir[2*i+1], b0 = phr[2*i], b1 = phr[2*i+1];
    wr[i] = pack8(a0 + b0, a1 + b1);
    a0 = piz[2*i]; a1 = piz[2*i+1]; b0 = phz[2*i]; b1 = phz[2*i+1];
    wz[i] = pack8(a0 + b0, a1 + b1);
    wn[i] = pack8(pin[2*i], pin[2*i+1]);
    wh[i] = pack8(phn[2*i], phn[2*i+1]);
}

__global__ __launch_bounds__(256) void prep_a(const float* __restrict__ in,
                                              i32x4* __restrict__ a)
{
    const int i = blockIdx.x * 256 + threadIdx.x;
    const float4* p = (const float4*)in;
    a[i] = pack8(p[2*i], p[2*i+1]);
}

// ---------------- main bf16 kernel ----------------
// LDS per buffer (24576 B): A[0,8K) Br[8K,12K) Bz[12K,16K) Bn[16K,20K) Bh[20K,24K)
// A region = 8 frags of 1KB; B regions = 4 frags of 1KB. Frag = 16 rows x 32 k,
// addr16 = frag*64 + chunk*16 + row  (linear in MFMA lane order -> DMA writes
// AND ds_read_b128 conflict-free).
// Staging per wave per step: 1 A-frag + 2 B-frags (gate wid>>1) = 3 gld16.
__global__ __launch_bounds__(THREADS, 4) void gru_bf16(
    const char* __restrict__ Abf, const char* __restrict__ Wr,
    const char* __restrict__ Wz, const char* __restrict__ Wn,
    const char* __restrict__ Wh,
    const float* __restrict__ hidden,
    const float* __restrict__ b_ir, const float* __restrict__ b_iz,
    const float* __restrict__ b_in, const float* __restrict__ b_hr,
    const float* __restrict__ b_hz, const float* __restrict__ b_hn,
    float* __restrict__ out)
{
    __shared__ __attribute__((aligned(128))) char smem[2 * LDSBUF];

    const int tid  = threadIdx.x;
    const int lane = tid & 63;
    const int wid  = tid >> 6;
    const int wm   = wid >> 2;   // 0..1 : M-wave (64 rows each)
    const int wn   = wid & 3;    // 0..3 : N-wave (16 cols each)

    // linear, b-fastest: consecutive blocks share the h-panel; A stays L3-hot.
    const int nb  = (int)blockIdx.x;
    const int bblk = nb & 63;        // 64 b-blocks
    const int hblk = nb >> 6;        // 64 h-blocks
    const int b0 = bblk * BM;
    const int h0 = hblk * FBN;

    // ---- staging assignment ----
    // A: wave w stages A-frag w (rows b0+w*16..+15).
    // B: gate g = wid>>1; frags f0=(wid&1)*2, f0+1 (rows h0+f*16..+15).
    const int g   = wid >> 1;
    const int f0  = (wid & 1) * 2;
    const size_t co = (size_t)(lane >> 4) * 16;     // k-chunk byte offset
    const char* gA = Abf + (size_t)(b0 + wid * 16 + (lane & 15)) * 8192 + co;
    const char* gWsel = (g == 0) ? Wr : (g == 1) ? Wz : (g == 2) ? Wn : Wh;
    const char* gB0 = gWsel + (size_t)(h0 + f0 * 16 + (lane & 15)) * 8192 + co;
    const char* gB1 = gWsel + (size_t)(h0 + (f0 + 1) * 16 + (lane & 15)) * 8192 + co;
    const int dA  = wid * 1024;
    const int dB0 = 8192 + g * 4096 + f0 * 1024;
    const int dB1 = dB0 + 1024;

    f32x4 accR[4], accZ[4], accN[4], accH[4];
#pragma unroll
    for (int mf = 0; mf < 4; ++mf) {
        accR[mf] = (f32x4)0.0f; accZ[mf] = (f32x4)0.0f;
        accN[mf] = (f32x4)0.0f; accH[mf] = (f32x4)0.0f;
    }

#define STAGE(s, p) do {                                        \
        const size_t kb = (size_t)(s) * 64;                     \
        char* lb = smem + (p) * LDSBUF;                         \
        gld16(gA + kb, lb + dA);                                \
        gld16(gB0 + kb, lb + dB0);                              \
        gld16(gB1 + kb, lb + dB1);                              \
    } while (0)

#define MM(acc, a, b) acc = __builtin_amdgcn_mfma_f32_16x16x32_bf16(a, b, acc, 0, 0, 0)

    STAGE(0, 0);
    STAGE(1, 1);
    asm volatile("s_waitcnt vmcnt(3)" ::: "memory");   // buf0's 3 loads done
    __builtin_amdgcn_s_barrier();

#pragma unroll 1
    for (int s = 0; s < NSTEP; ++s) {
        const int p = s & 1;
        const char* cb = smem + p * LDSBUF;
        bf16x8 af[4], fr, fz, fn, fh;
#pragma unroll
        for (int mf = 0; mf < 4; ++mf)
            af[mf] = *(const bf16x8*)(cb + (wm * 4 + mf) * 1024 + (lane << 4));
        {
            const int fo = wn * 1024 + (lane << 4);
            fr = *(const bf16x8*)(cb + 8192  + fo);
            fz = *(const bf16x8*)(cb + 12288 + fo);
            fn = *(const bf16x8*)(cb + 16384 + fo);
            fh = *(const bf16x8*)(cb + 20480 + fo);
        }
        asm volatile("s_waitcnt lgkmcnt(0)" ::: "memory");
        __builtin_amdgcn_sched_barrier(0);
        __builtin_amdgcn_s_barrier();            // all waves done reading buf p
        if (s < NSTEP - 2) STAGE(s + 2, p);      // async overwrite of buf p
        __builtin_amdgcn_s_setprio(1);
#pragma unroll
        for (int mf = 0; mf < 4; ++mf) {
            MM(accR[mf], af[mf], fr);
            MM(accZ[mf], af[mf], fz);
            MM(accN[mf], af[mf], fn);
            MM(accH[mf], af[mf], fh);
        }
        __builtin_amdgcn_s_setprio(0);
        if (s < NSTEP - 2)      { asm volatile("s_waitcnt vmcnt(3)" ::: "memory"); }
        else if (s == NSTEP - 2){ asm volatile("s_waitcnt vmcnt(0)" ::: "memory"); }
        __builtin_amdgcn_s_barrier();            // buf[(s+1)&1] staged
    }

    // ---- epilogue: biases + gate math + combine, fp32 out ----
    const int r4 = (lane >> 4) * 4;
    const int cn = lane & 15;
    {
        const int h = h0 + wn * 16 + cn;
        const float br = b_ir[h] + b_hr[h];
        const float bz = b_iz[h] + b_hz[h];
        const float bn = b_in[h];
        const float bh = b_hn[h];
#pragma unroll
        for (int mf = 0; mf < 4; ++mf) {
            const int brow = b0 + wm * 64 + mf * 16 + r4;
#pragma unroll
            for (int j = 0; j < 4; ++j) {
                const size_t idx = (size_t)(brow + j) * H_DIM + h;
                const float r = sigmoidf_(accR[mf][j] + br);
                const float z = sigmoidf_(accZ[mf][j] + bz);
                const float n = sigmoidf_(accN[mf][j] + bn + r * (accH[mf][j] + bh));
                out[idx] = (1.0f - z) * hidden[idx] + z * n;
            }
        }
    }
#undef STAGE
#undef MM
}

// ---------------- fallback: round-1 fp32-staged kernel (known passing) ----------------
__global__ __launch_bounds__(THREADS, 2) void gru_fused_f32(
    const float* __restrict__ input, const float* __restrict__ hidden,
    const float* __restrict__ w_ir, const float* __restrict__ b_ir,
    const float* __restrict__ w_iz, const float* __restrict__ b_iz,
    const float* __restrict__ w_in, const float* __restrict__ b_in,
    const float* __restrict__ w_hr, const float* __restrict__ b_hr,
    const float* __restrict__ w_hz, const float* __restrict__ b_hz,
    const float* __restrict__ w_hn, const float* __restrict__ b_hn,
    float* __restrict__ out)
{
    __shared__ int smem[2 * 10240];
    const int tid  = threadIdx.x;
    const int lane = tid & 63;
    const int wid  = tid >> 6;
    const int wm   = wid >> 2;
    const int wn   = wid & 3;
    const int bblk = blockIdx.x & 63;
    const int hblk = blockIdx.x >> 6;
    const int b0 = bblk * BM;
    const int h0 = hblk * BN;
    const int srow = tid >> 2;
    const int sc   = tid & 3;
    const float4* gA  = (const float4*)(input + (size_t)(b0 + srow) * D_DIM + sc * 8);
    const size_t woff = (size_t)(h0 + srow) * D_DIM + sc * 8;
    const float4* gIr = (const float4*)(w_ir + woff);
    const float4* gHr = (const float4*)(w_hr + woff);
    const float4* gIz = (const float4*)(w_iz + woff);
    const float4* gHz = (const float4*)(w_hz + woff);
    const float4* gIn = (const float4*)(w_in + woff);
    const float4* gHn = (const float4*)(w_hn + woff);
    const int wr_ints = (srow >> 4) * 256 + ((sc * 16 + (srow & 15)) * 4);

    f32x4 accR[4][2], accZ[4][2], accN[4][2], accH[4][2];
#pragma unroll
    for (int mf = 0; mf < 4; ++mf)
#pragma unroll
        for (int nf = 0; nf < 2; ++nf) {
            accR[mf][nf] = (f32x4)0.0f; accZ[mf][nf] = (f32x4)0.0f;
            accN[mf][nf] = (f32x4)0.0f; accH[mf][nf] = (f32x4)0.0f;
        }
    float4 La0, La1, Lr0, Lr1, Lr2, Lr3, Lz0, Lz1, Lz2, Lz3, Ln0, Ln1, Lh0, Lh1;
#define LOADREGS(s) do { const int o = (s) * 8;                          \
        La0 = gA[o];  La1 = gA[o + 1];                                   \
        Lr0 = gIr[o]; Lr1 = gIr[o + 1]; Lr2 = gHr[o]; Lr3 = gHr[o + 1];  \
        Lz0 = gIz[o]; Lz1 = gIz[o + 1]; Lz2 = gHz[o]; Lz3 = gHz[o + 1];  \
        Ln0 = gIn[o]; Ln1 = gIn[o + 1];                                  \
        Lh0 = gHn[o]; Lh1 = gHn[o + 1]; } while (0)
#define WRITELDS(pp) do { const int wb = (pp) * 10240 + wr_ints;          \
        *(i32x4*)&smem[wb]        = pack8(La0, La1);                      \
        *(i32x4*)&smem[wb + 2048] = pack8(Lr0 + Lr2, Lr1 + Lr3);          \
        *(i32x4*)&smem[wb + 4096] = pack8(Lz0 + Lz2, Lz1 + Lz3);          \
        *(i32x4*)&smem[wb + 6144] = pack8(Ln0, Ln1);                      \
        *(i32x4*)&smem[wb + 8192] = pack8(Lh0, Lh1); } while (0)
#define COMPUTE(pp) do {                                                  \
        const int cb = (pp) * 10240;                                      \
        const bf16x8* Af = (const bf16x8*)&smem[cb];                      \
        const bf16x8* Br = (const bf16x8*)&smem[cb + 2048];               \
        const bf16x8* Bz = (const bf16x8*)&smem[cb + 4096];               \
        const bf16x8* Bn = (const bf16x8*)&smem[cb + 6144];               \
        const bf16x8* Bh = (const bf16x8*)&smem[cb + 8192];               \
        bf16x8 afr[4];                                                    \
        _Pragma("unroll")                                                 \
        for (int mf = 0; mf < 4; ++mf)                                    \
            afr[mf] = Af[(wm * 4 + mf) * 64 + lane];                      \
        _Pragma("unroll")                                                 \
        for (int nf = 0; nf < 2; ++nf) {                                  \
            const int bi = (wn * 2 + nf) * 64 + lane;                     \
            bf16x8 fr = Br[bi], fz = Bz[bi], fn = Bn[bi], fh = Bh[bi];    \
            _Pragma("unroll")                                             \
            for (int mf = 0; mf < 4; ++mf) {                              \
                accR[mf][nf] = __builtin_amdgcn_mfma_f32_16x16x32_bf16(afr[mf], fr, accR[mf][nf], 0, 0, 0); \
                accZ[mf][nf] = __builtin_amdgcn_mfma_f32_16x16x32_bf16(afr[mf], fz, accZ[mf][nf], 0, 0, 0); \
                accN[mf][nf] = __builtin_amdgcn_mfma_f32_16x16x32_bf16(afr[mf], fn, accN[mf][nf], 0, 0, 0); \
                accH[mf][nf] = __builtin_amdgcn_mfma_f32_16x16x32_bf16(afr[mf], fh, accH[mf][nf], 0, 0, 0); \
            }                                                             \
        } } while (0)
    LOADREGS(0);
    WRITELDS(0);
    __syncthreads();
#pragma unroll 1
    for (int s = 0; s < NSTEP; ++s) {
        if (s + 1 < NSTEP) LOADREGS(s + 1);
        COMPUTE(s & 1);
        if (s + 1 < NSTEP) { WRITELDS((s + 1) & 1); __syncthreads(); }
    }
    const int r4 = (lane >> 4) * 4;
    const int cn = lane & 15;
#pragma unroll
    for (int nf = 0; nf < 2; ++nf) {
        const int h = h0 + wn * 32 + nf * 16 + cn;
        const float br = b_ir[h] + b_hr[h];
        const float bz = b_iz[h] + b_hz[h];
        const float bn = b_in[h];
        const float bh = b_hn[h];
#pragma unroll
        for (int mf = 0; mf < 4; ++mf) {
            const int brow = b0 + wm * 64 + mf * 16 + r4;
#pragma unroll
            for (int j = 0; j < 4; ++j) {
                const size_t idx = (size_t)(brow + j) * H_DIM + h;
                const float r = sigmoidf_(accR[mf][nf][j] + br);
                const float z = sigmoidf_(accZ[mf][nf][j] + bz);
                const float n = sigmoidf_(accN[mf][nf][j] + bn + r * (accH[mf][nf][j] + bh));
                out[idx] = (1.0f - z) * hidden[idx] + z * n;
            }
        }
    }
#undef LOADREGS
#undef WRITELDS
#undef COMPUTE
}

extern "C" void kernel_launch(void* const* d_in, const int* in_sizes, int n_in,
                              void* d_out, int out_size, void* d_ws, size_t ws_size,
                              hipStream_t stream) {
    const float* input  = (const float*)d_in[0];
    const float* hidden = (const float*)d_in[1];
    const float* w_ir = (const float*)d_in[2];  const float* b_ir = (const float*)d_in[3];
    const float* w_iz = (const float*)d_in[4];  const float* b_iz = (const float*)d_in[5];
    const float* w_in = (const float*)d_in[6];  const float* b_in = (const float*)d_in[7];
    const float* w_hr = (const float*)d_in[8];  const float* b_hr = (const float*)d_in[9];
    const float* w_hz = (const float*)d_in[10]; const float* b_hz = (const float*)d_in[11];
    const float* w_hn = (const float*)d_in[12]; const float* b_hn = (const float*)d_in[13];
    float* out = (float*)d_out;

    if (ws_size >= WS_NEED) {
        char* ws = (char*)d_ws;
        prep_w<<<dim3(8192), dim3(256), 0, stream>>>(
            w_ir, w_hr, w_iz, w_hz, w_in, w_hn,
            (i32x4*)(ws + WS_WR), (i32x4*)(ws + WS_WZ),
            (i32x4*)(ws + WS_WN), (i32x4*)(ws + WS_WH));
        prep_a<<<dim3(16384), dim3(256), 0, stream>>>(input, (i32x4*)(ws + WS_A));
        gru_bf16<<<dim3(4096), dim3(THREADS), 0, stream>>>(
            ws + WS_A, ws + WS_WR, ws + WS_WZ, ws + WS_WN, ws + WS_WH,
            hidden, b_ir, b_iz, b_in, b_hr, b_hz, b_hn, out);
    } else {
        gru_fused_f32<<<dim3(2048), dim3(THREADS), 0, stream>>>(
            input, hidden, w_ir, b_ir, w_iz, b_iz, w_in, b_in,
            w_hr, b_hr, w_hz, b_hz, w_hn, b_hn, out);
    }
}

// Round 6
// 1348.303 us; speedup vs baseline: 1.1828x; 1.1828x over previous
//
#include <hip/hip_runtime.h>
#include <hip/hip_bf16.h>

// out = (1-z)*hidden + z*n
//   r = sig(in·(w_ir+w_hr)^T + b_ir+b_hr)
//   z = sig(in·(w_iz+w_hz)^T + b_iz+b_hz)
//   n = sig(in·w_in^T + b_in + r*(in·w_hn^T + b_hn))
// Fast path: prepass folds/converts weights+input to bf16 in d_ws, then an
// m201-style 4-phase-per-K-tile fused GEMM: BM=256, BK=64, per-gate BN=64,
// 8 waves, 128KB LDS dbuf, per-phase {ds_read || gld16 -> barrier -> lgkm0 ->
// setprio(1) -> 16 MFMA}, one covered vmcnt(0) per tile.
// Fallback (ws too small): round-1 fp32-staged kernel (known passing).

#define THREADS 512
#define B_DIM 8192
#define D_DIM 4096
#define H_DIM 4096
#define BM 256
#define GBN 64              // per-gate output cols per block
#define BK 64
#define NT (D_DIM / BK)     // 64 K-tiles
#define DBUF 65536          // bytes per LDS buffer: A 32KB + 4x8KB B

// ws layout (bytes)
#define WS_WR 0
#define WS_WZ 33554432
#define WS_WN 67108864
#define WS_WH 100663296
#define WS_A  134217728
#define WS_NEED 201326592ULL

typedef __attribute__((ext_vector_type(8))) short bf16x8;
typedef __attribute__((ext_vector_type(4))) float f32x4;
typedef __attribute__((ext_vector_type(4))) int i32x4;

__device__ __forceinline__ unsigned f2bf(float f) {
    union { float f; unsigned u; } v; v.f = f;
    return (v.u + 0x7FFFu + ((v.u >> 16) & 1u)) >> 16;   // RNE
}
__device__ __forceinline__ unsigned pk(float a, float b) {
    return (f2bf(a) & 0xFFFFu) | (f2bf(b) << 16);
}
__device__ __forceinline__ i32x4 pack8(float4 x, float4 y) {
    i32x4 r;
    r[0] = (int)pk(x.x, x.y); r[1] = (int)pk(x.z, x.w);
    r[2] = (int)pk(y.x, y.y); r[3] = (int)pk(y.z, y.w);
    return r;
}
__device__ __forceinline__ float sigmoidf_(float x) {
    return 1.0f / (1.0f + __expf(-x));
}
__device__ __forceinline__ void gld16(const void* g, void* l) {
    __builtin_amdgcn_global_load_lds(
        (const __attribute__((address_space(1))) unsigned*)g,
        (__attribute__((address_space(3))) unsigned*)l, 16, 0, 0);
}

// ---------------- prepass kernels ----------------
__global__ __launch_bounds__(256) void prep_w(
    const float* __restrict__ ir, const float* __restrict__ hr,
    const float* __restrict__ iz, const float* __restrict__ hz,
    const float* __restrict__ inw, const float* __restrict__ hn,
    i32x4* __restrict__ wr, i32x4* __restrict__ wz,
    i32x4* __restrict__ wn, i32x4* __restrict__ wh)
{
    const int i = blockIdx.x * 256 + threadIdx.x;     // chunk of 8 floats
    const float4* pir = (const float4*)ir; const float4* phr = (const float4*)hr;
    const float4* piz = (const float4*)iz; const float4* phz = (const float4*)hz;
    const float4* pin = (const float4*)inw; const float4* phn = (const float4*)hn;
    float4 a0 = pir[2*i], a1 = pir[2*i+1], b0 = phr[2*i], b1 = phr[2*i+1];
    wr[i] = pack8(a0 + b0, a1 + b1);
    a0 = piz[2*i]; a1 = piz[2*i+1]; b0 = phz[2*i]; b1 = phz[2*i+1];
    wz[i] = pack8(a0 + b0, a1 + b1);
    wn[i] = pack8(pin[2*i], pin[2*i+1]);
    wh[i] = pack8(phn[2*i], phn[2*i+1]);
}

__global__ __launch_bounds__(256) void prep_a(const float* __restrict__ in,
                                              i32x4* __restrict__ a)
{
    const int i = blockIdx.x * 256 + threadIdx.x;
    const float4* p = (const float4*)in;
    a[i] = pack8(p[2*i], p[2*i+1]);
}

// ---------------- main bf16 kernel (m201-style 4-phase) ----------------
// LDS per buffer (64 KB):
//   A  [0, 32K):  frag(mfr 0..15, kk 0..1) at (mfr*2+kk)*1024
//   Bg [32K+g*8K, +8K): frag(nfr 0..3, kk) at (nfr*2+kk)*1024
// Frag = 16 rows x 32 k bf16, 1 KB, lane slot l = (row l&15, k-chunk l>>4):
// linear in MFMA lane order -> DMA writes AND ds_read_b128 conflict-free.
//
// Per K-tile t (reads dbuf p=t&1; stages tile t+1 into dbuf p^1):
//  ph1: rd af[mh0](8) + fb[g0,g1](4) | stage A(4)+B0(2) | bar lgkm0 prio1 16MM
//  ph2: rd fb[g2,g3](4)              | stage B1(2)      | bar lgkm0 prio1 16MM
//  ph3: rd af[mh1](8)                |                  | bar lgkm0 prio1 16MM
//  ph4:                              |                  | bar prio1 16MM
//       vmcnt(0) [covered: stages issued 2-3 phases earlier] ; bar
__global__ __launch_bounds__(THREADS, 2) void gru_bf16(
    const char* __restrict__ Abf, const char* __restrict__ Wr,
    const char* __restrict__ Wz, const char* __restrict__ Wn,
    const char* __restrict__ Wh,
    const float* __restrict__ hidden,
    const float* __restrict__ b_ir, const float* __restrict__ b_iz,
    const float* __restrict__ b_in, const float* __restrict__ b_hr,
    const float* __restrict__ b_hz, const float* __restrict__ b_hn,
    float* __restrict__ out)
{
    __shared__ __attribute__((aligned(128))) char smem[2 * DBUF];

    const int tid  = threadIdx.x;
    const int lane = tid & 63;
    const int wid  = tid >> 6;
    const int wm   = wid >> 2;     // 0..1 : M-half (128 rows)
    const int wn   = wid & 3;      // 0..3 : 16-col slice (nfr = wn)

    // linear, b-fastest: consecutive blocks share the weight panel; A L3-hot.
    const int nb   = (int)blockIdx.x;
    const int bblk = nb & 31;       // 32 b-blocks
    const int hblk = nb >> 5;       // 64 h-blocks
    const int b0 = bblk * BM;
    const int h0 = hblk * GBN;

    // staging roles: wave stages A-frags mfr={wid, wid+8}, and gate sg's
    // B-frags nfr=sn0 (ph1) and 2+sn0 (ph2), each both kk.
    const int sg  = wid >> 1;
    const int sn0 = wid & 1;
    const char* gWsel = (sg == 0) ? Wr : (sg == 1) ? Wz : (sg == 2) ? Wn : Wh;
    const char* pA = Abf + (size_t)(b0 + (lane & 15)) * 8192 + ((lane >> 4) * 16);
    const char* pB = gWsel + (size_t)(h0 + (lane & 15)) * 8192 + ((lane >> 4) * 16);
    const int dB = 32768 + sg * 8192;

    f32x4 acc[4][8];
#pragma unroll
    for (int g = 0; g < 4; ++g)
#pragma unroll
        for (int m = 0; m < 8; ++m) acc[g][m] = (f32x4)0.0f;

#define STAGE_PH1(t, d) do { const size_t ko = (size_t)(t) * 128;              \
        gld16(pA + (size_t)wid * 131072 + ko,            smem + (d) + (wid * 2) * 1024);        \
        gld16(pA + (size_t)wid * 131072 + ko + 64,       smem + (d) + (wid * 2 + 1) * 1024);    \
        gld16(pA + (size_t)(wid + 8) * 131072 + ko,      smem + (d) + ((wid + 8) * 2) * 1024);  \
        gld16(pA + (size_t)(wid + 8) * 131072 + ko + 64, smem + (d) + ((wid + 8) * 2 + 1) * 1024); \
        gld16(pB + (size_t)sn0 * 131072 + ko,            smem + (d) + dB + (sn0 * 2) * 1024);   \
        gld16(pB + (size_t)sn0 * 131072 + ko + 64,       smem + (d) + dB + (sn0 * 2 + 1) * 1024); \
    } while (0)

#define STAGE_PH2(t, d) do { const size_t ko = (size_t)(t) * 128;              \
        gld16(pB + (size_t)(2 + sn0) * 131072 + ko,      smem + (d) + dB + ((2 + sn0) * 2) * 1024); \
        gld16(pB + (size_t)(2 + sn0) * 131072 + ko + 64, smem + (d) + dB + ((2 + sn0) * 2 + 1) * 1024); \
    } while (0)

#define RD_AF(mhq) do {                                                        \
        _Pragma("unroll")                                                      \
        for (int mf = 0; mf < 4; ++mf)                                         \
            _Pragma("unroll")                                                  \
            for (int kk = 0; kk < 2; ++kk)                                     \
                af[mf][kk] = *(const bf16x8*)(cb + ((wm * 8 + (mhq) * 4 + mf) * 2 + kk) * 1024 + (lane << 4)); \
    } while (0)

#define RD_FB(g) do {                                                          \
        _Pragma("unroll")                                                      \
        for (int kk = 0; kk < 2; ++kk)                                         \
            fb[g][kk] = *(const bf16x8*)(cb + 32768 + (g) * 8192 + (wn * 2 + kk) * 1024 + (lane << 4)); \
    } while (0)

#define MM(acc_, a_, b_) acc_ = __builtin_amdgcn_mfma_f32_16x16x32_bf16(a_, b_, acc_, 0, 0, 0)

#define PH_MFMA(g0_, ab_) do {                                                 \
        __builtin_amdgcn_s_barrier();                                          \
        asm volatile("s_waitcnt lgkmcnt(0)" ::: "memory");                     \
        __builtin_amdgcn_sched_barrier(0);                                     \
        __builtin_amdgcn_s_setprio(1);                                         \
        _Pragma("unroll")                                                      \
        for (int g = (g0_); g < (g0_) + 2; ++g)                                \
            _Pragma("unroll")                                                  \
            for (int mf = 0; mf < 4; ++mf)                                     \
                _Pragma("unroll")                                              \
                for (int kk = 0; kk < 2; ++kk)                                 \
                    MM(acc[g][(ab_) * 4 + mf], af[mf][kk], fb[g][kk]);         \
        __builtin_amdgcn_s_setprio(0);                                         \
    } while (0)

    // ---- prologue: stage tile 0 into dbuf0 ----
    STAGE_PH1(0, 0);
    STAGE_PH2(0, 0);
    asm volatile("s_waitcnt vmcnt(0)" ::: "memory");
    __builtin_amdgcn_s_barrier();

#pragma unroll 1
    for (int t = 0; t < NT; ++t) {
        const int p = t & 1;
        const char* cb = smem + p * DBUF;
        const int d = (p ^ 1) * DBUF;
        const bool stg = (t < NT - 1);
        bf16x8 af[4][2], fb[4][2];

        // ---- ph1: af[mh0], fb[g0,g1]; stage A + B0 of t+1 ----
        RD_AF(0);
        RD_FB(0); RD_FB(1);
        if (stg) STAGE_PH1(t + 1, d);
        PH_MFMA(0, 0);

        // ---- ph2: fb[g2,g3]; stage B1 of t+1 ----
        RD_FB(2); RD_FB(3);
        if (stg) STAGE_PH2(t + 1, d);
        PH_MFMA(2, 0);

        // ---- ph3: af[mh1] ----
        RD_AF(1);
        PH_MFMA(0, 1);

        // ---- ph4 ----
        PH_MFMA(2, 1);

        // tile boundary: publish t+1's stages (issued 2-3 phases ago -> covered)
        if (stg) { asm volatile("s_waitcnt vmcnt(0)" ::: "memory"); }
        __builtin_amdgcn_s_barrier();
    }

    // ---- epilogue: biases + gate math + combine, fp32 out ----
    const int r4 = (lane >> 4) * 4;
    const int cn = lane & 15;
    {
        const int h = h0 + wn * 16 + cn;
        const float br = b_ir[h] + b_hr[h];
        const float bz = b_iz[h] + b_hz[h];
        const float bn = b_in[h];
        const float bh = b_hn[h];
#pragma unroll
        for (int m = 0; m < 8; ++m) {
            const int brow = b0 + wm * 128 + m * 16 + r4;
#pragma unroll
            for (int j = 0; j < 4; ++j) {
                const size_t idx = (size_t)(brow + j) * H_DIM + h;
                const float r = sigmoidf_(acc[0][m][j] + br);
                const float z = sigmoidf_(acc[1][m][j] + bz);
                const float n = sigmoidf_(acc[2][m][j] + bn + r * (acc[3][m][j] + bh));
                out[idx] = (1.0f - z) * hidden[idx] + z * n;
            }
        }
    }
#undef STAGE_PH1
#undef STAGE_PH2
#undef RD_AF
#undef RD_FB
#undef MM
#undef PH_MFMA
}

// ---------------- fallback: round-1 fp32-staged kernel (known passing) ----------------
__global__ __launch_bounds__(THREADS, 2) void gru_fused_f32(
    const float* __restrict__ input, const float* __restrict__ hidden,
    const float* __restrict__ w_ir, const float* __restrict__ b_ir,
    const float* __restrict__ w_iz, const float* __restrict__ b_iz,
    const float* __restrict__ w_in, const float* __restrict__ b_in,
    const float* __restrict__ w_hr, const float* __restrict__ b_hr,
    const float* __restrict__ w_hz, const float* __restrict__ b_hz,
    const float* __restrict__ w_hn, const float* __restrict__ b_hn,
    float* __restrict__ out)
{
    __shared__ int smem[2 * 10240];
    const int tid  = threadIdx.x;
    const int lane = tid & 63;
    const int wid  = tid >> 6;
    const int wm   = wid >> 2;
    const int wn   = wid & 3;
    const int bblk = blockIdx.x & 63;
    const int hblk = blockIdx.x >> 6;
    const int b0 = bblk * 128;
    const int h0 = hblk * 128;
    const int srow = tid >> 2;
    const int sc   = tid & 3;
    const float4* gA  = (const float4*)(input + (size_t)(b0 + srow) * D_DIM + sc * 8);
    const size_t woff = (size_t)(h0 + srow) * D_DIM + sc * 8;
    const float4* gIr = (const float4*)(w_ir + woff);
    const float4* gHr = (const float4*)(w_hr + woff);
    const float4* gIz = (const float4*)(w_iz + woff);
    const float4* gHz = (const float4*)(w_hz + woff);
    const float4* gIn = (const float4*)(w_in + woff);
    const float4* gHn = (const float4*)(w_hn + woff);
    const int wr_ints = (srow >> 4) * 256 + ((sc * 16 + (srow & 15)) * 4);

    f32x4 accR[4][2], accZ[4][2], accN[4][2], accH[4][2];
#pragma unroll
    for (int mf = 0; mf < 4; ++mf)
#pragma unroll
        for (int nf = 0; nf < 2; ++nf) {
            accR[mf][nf] = (f32x4)0.0f; accZ[mf][nf] = (f32x4)0.0f;
            accN[mf][nf] = (f32x4)0.0f; accH[mf][nf] = (f32x4)0.0f;
        }
    float4 La0, La1, Lr0, Lr1, Lr2, Lr3, Lz0, Lz1, Lz2, Lz3, Ln0, Ln1, Lh0, Lh1;
#define LOADREGS(s) do { const int o = (s) * 8;                          \
        La0 = gA[o];  La1 = gA[o + 1];                                   \
        Lr0 = gIr[o]; Lr1 = gIr[o + 1]; Lr2 = gHr[o]; Lr3 = gHr[o + 1];  \
        Lz0 = gIz[o]; Lz1 = gIz[o + 1]; Lz2 = gHz[o]; Lz3 = gHz[o + 1];  \
        Ln0 = gIn[o]; Ln1 = gIn[o + 1];                                  \
        Lh0 = gHn[o]; Lh1 = gHn[o + 1]; } while (0)
#define WRITELDS(pp) do { const int wb = (pp) * 10240 + wr_ints;          \
        *(i32x4*)&smem[wb]        = pack8(La0, La1);                      \
        *(i32x4*)&smem[wb + 2048] = pack8(Lr0 + Lr2, Lr1 + Lr3);          \
        *(i32x4*)&smem[wb + 4096] = pack8(Lz0 + Lz2, Lz1 + Lz3);          \
        *(i32x4*)&smem[wb + 6144] = pack8(Ln0, Ln1);                      \
        *(i32x4*)&smem[wb + 8192] = pack8(Lh0, Lh1); } while (0)
#define COMPUTE(pp) do {                                                  \
        const int cb = (pp) * 10240;                                      \
        const bf16x8* Af = (const bf16x8*)&smem[cb];                      \
        const bf16x8* Br = (const bf16x8*)&smem[cb + 2048];               \
        const bf16x8* Bz = (const bf16x8*)&smem[cb + 4096];               \
        const bf16x8* Bn = (const bf16x8*)&smem[cb + 6144];               \
        const bf16x8* Bh = (const bf16x8*)&smem[cb + 8192];               \
        bf16x8 afr[4];                                                    \
        _Pragma("unroll")                                                 \
        for (int mf = 0; mf < 4; ++mf)                                    \
            afr[mf] = Af[(wm * 4 + mf) * 64 + lane];                      \
        _Pragma("unroll")                                                 \
        for (int nf = 0; nf < 2; ++nf) {                                  \
            const int bi = (wn * 2 + nf) * 64 + lane;                     \
            bf16x8 fr = Br[bi], fz = Bz[bi], fn = Bn[bi], fh = Bh[bi];    \
            _Pragma("unroll")                                             \
            for (int mf = 0; mf < 4; ++mf) {                              \
                accR[mf][nf] = __builtin_amdgcn_mfma_f32_16x16x32_bf16(afr[mf], fr, accR[mf][nf], 0, 0, 0); \
                accZ[mf][nf] = __builtin_amdgcn_mfma_f32_16x16x32_bf16(afr[mf], fz, accZ[mf][nf], 0, 0, 0); \
                accN[mf][nf] = __builtin_amdgcn_mfma_f32_16x16x32_bf16(afr[mf], fn, accN[mf][nf], 0, 0, 0); \
                accH[mf][nf] = __builtin_amdgcn_mfma_f32_16x16x32_bf16(afr[mf], fh, accH[mf][nf], 0, 0, 0); \
            }                                                             \
        } } while (0)
    LOADREGS(0);
    WRITELDS(0);
    __syncthreads();
#pragma unroll 1
    for (int s = 0; s < 128; ++s) {
        if (s + 1 < 128) LOADREGS(s + 1);
        COMPUTE(s & 1);
        if (s + 1 < 128) { WRITELDS((s + 1) & 1); __syncthreads(); }
    }
    const int r4 = (lane >> 4) * 4;
    const int cn = lane & 15;
#pragma unroll
    for (int nf = 0; nf < 2; ++nf) {
        const int h = h0 + wn * 32 + nf * 16 + cn;
        const float br = b_ir[h] + b_hr[h];
        const float bz = b_iz[h] + b_hz[h];
        const float bn = b_in[h];
        const float bh = b_hn[h];
#pragma unroll
        for (int mf = 0; mf < 4; ++mf) {
            const int brow = b0 + wm * 64 + mf * 16 + r4;
#pragma unroll
            for (int j = 0; j < 4; ++j) {
                const size_t idx = (size_t)(brow + j) * H_DIM + h;
                const float r = sigmoidf_(accR[mf][nf][j] + br);
                const float z = sigmoidf_(accZ[mf][nf][j] + bz);
                const float n = sigmoidf_(accN[mf][nf][j] + bn + r * (accH[mf][nf][j] + bh));
                out[idx] = (1.0f - z) * hidden[idx] + z * n;
            }
        }
    }
#undef LOADREGS
#undef WRITELDS
#undef COMPUTE
}

extern "C" void kernel_launch(void* const* d_in, const int* in_sizes, int n_in,
                              void* d_out, int out_size, void* d_ws, size_t ws_size,
                              hipStream_t stream) {
    const float* input  = (const float*)d_in[0];
    const float* hidden = (const float*)d_in[1];
    const float* w_ir = (const float*)d_in[2];  const float* b_ir = (const float*)d_in[3];
    const float* w_iz = (const float*)d_in[4];  const float* b_iz = (const float*)d_in[5];
    const float* w_in = (const float*)d_in[6];  const float* b_in = (const float*)d_in[7];
    const float* w_hr = (const float*)d_in[8];  const float* b_hr = (const float*)d_in[9];
    const float* w_hz = (const float*)d_in[10]; const float* b_hz = (const float*)d_in[11];
    const float* w_hn = (const float*)d_in[12]; const float* b_hn = (const float*)d_in[13];
    float* out = (float*)d_out;

    if (ws_size >= WS_NEED) {
        char* ws = (char*)d_ws;
        prep_w<<<dim3(8192), dim3(256), 0, stream>>>(
            w_ir, w_hr, w_iz, w_hz, w_in, w_hn,
            (i32x4*)(ws + WS_WR), (i32x4*)(ws + WS_WZ),
            (i32x4*)(ws + WS_WN), (i32x4*)(ws + WS_WH));
        prep_a<<<dim3(16384), dim3(256), 0, stream>>>(input, (i32x4*)(ws + WS_A));
        gru_bf16<<<dim3((B_DIM / BM) * (H_DIM / GBN)), dim3(THREADS), 0, stream>>>(
            ws + WS_A, ws + WS_WR, ws + WS_WZ, ws + WS_WN, ws + WS_WH,
            hidden, b_ir, b_iz, b_in, b_hr, b_hz, b_hn, out);
    } else {
        gru_fused_f32<<<dim3(2048), dim3(THREADS), 0, stream>>>(
            input, hidden, w_ir, b_ir, w_iz, b_iz, w_in, b_in,
            w_hr, b_hr, w_hz, b_hz, w_hn, b_hn, out);
    }
}